// Round 4
// baseline (163.293 us; speedup 1.0000x reference)
//
#include <hip/hip_runtime.h>
#include <math.h>

#define NTOK 16384      // 4 * 4096 tokens
#define DIM 2048
#define NEXP 64
#define TOPK 8
#define BT 32           // tokens per block
#define KC 16           // one numpy-einsum 4x-unrolled SIMD block (16 floats)
#define NCHUNK (DIM / KC)   // 128
#define PADK 20         // LDS row stride (floats), float4-aligned, bank-spread
#define NBLK (NTOK / BT)    // 512 blocks

// Replicates np.einsum('nd,ed->ne') float32 semantics (SSE2-baseline npyv):
// 4 stride-4 serial lane chains, blocks of 16 with nested adds
// c = p0 + (p1 + (p2 + (p3 + c))), final combine (c0+c2)+(c1+c3). No FMA.
__global__ __launch_bounds__(256) void moe_gate_np(
    const float* __restrict__ h, const float* __restrict__ W,
    float* __restrict__ out, float* __restrict__ wsum)
{
#pragma clang fp contract(off)
    __shared__ float sA[BT * PADK];          // h tile   [32][20]
    __shared__ float sB[NEXP * PADK];        // W tile   [64][20]
    __shared__ float lg[BT][NEXP + 2];       // logits -> p values

    const int tid = threadIdx.x;
    const int blk = blockIdx.x;
    const long tok0 = (long)blk * BT;
    const float* hA = h + tok0 * DIM;

    // staging: sB by all 256 threads (64 rows x 16 cols), sA by tid<128
    const int sr = tid >> 2;                 // 0..63
    const int sc = (tid & 3) * 4;            // 0,4,8,12

    float4 pa, pb;
    pb = *(const float4*)(W + (long)sr * DIM + sc);
    if (tid < 128) pa = *(const float4*)(hA + (long)sr * DIM + sc);

    // compute map: 2 tokens x 4 experts per thread
    const int tx = tid & 15;                 // expert base
    const int ty = tid >> 4;                 // token base (0..15)

    float4 c[2][4];
    #pragma unroll
    for (int i = 0; i < 2; ++i)
        #pragma unroll
        for (int j = 0; j < 4; ++j) c[i][j] = make_float4(0.f, 0.f, 0.f, 0.f);

    for (int kc = 0; kc < NCHUNK; ++kc) {
        __syncthreads();
        *(float4*)&sB[sr * PADK + sc] = pb;
        if (tid < 128) *(float4*)&sA[sr * PADK + sc] = pa;
        __syncthreads();

        if (kc + 1 < NCHUNK) {               // prefetch next block under compute
            const long ko = (long)(kc + 1) * KC;
            pb = *(const float4*)(W + (long)sr * DIM + ko + sc);
            if (tid < 128) pa = *(const float4*)(hA + (long)sr * DIM + ko + sc);
        }

        float4 A[2][4], B[4][4];
        #pragma unroll
        for (int i = 0; i < 2; ++i) {
            const float* base = &sA[(ty + 16 * i) * PADK];
            #pragma unroll
            for (int v = 0; v < 4; ++v) A[i][v] = *(const float4*)(base + 4 * v);
        }
        #pragma unroll
        for (int j = 0; j < 4; ++j) {
            const float* base = &sB[(tx + 16 * j) * PADK];
            #pragma unroll
            for (int v = 0; v < 4; ++v) B[j][v] = *(const float4*)(base + 4 * v);
        }

        #pragma unroll
        for (int i = 0; i < 2; ++i)
            #pragma unroll
            for (int j = 0; j < 4; ++j) {
                float4& cc = c[i][j];
                float t;
                t = A[i][3].x * B[j][3].x + cc.x;   // p3 + c (mul,add separate: contract off)
                t = A[i][2].x * B[j][2].x + t;
                t = A[i][1].x * B[j][1].x + t;
                cc.x = A[i][0].x * B[j][0].x + t;
                t = A[i][3].y * B[j][3].y + cc.y;
                t = A[i][2].y * B[j][2].y + t;
                t = A[i][1].y * B[j][1].y + t;
                cc.y = A[i][0].y * B[j][0].y + t;
                t = A[i][3].z * B[j][3].z + cc.z;
                t = A[i][2].z * B[j][2].z + t;
                t = A[i][1].z * B[j][1].z + t;
                cc.z = A[i][0].z * B[j][0].z + t;
                t = A[i][3].w * B[j][3].w + cc.w;
                t = A[i][2].w * B[j][2].w + t;
                t = A[i][1].w * B[j][1].w + t;
                cc.w = A[i][0].w * B[j][0].w + t;
            }
    }

    // horizontal combine: (l0+l2)+(l1+l3)  (npyv_sum_f32 SSE2 order)
    #pragma unroll
    for (int i = 0; i < 2; ++i)
        #pragma unroll
        for (int j = 0; j < 4; ++j) {
            const float4 v = c[i][j];
            lg[ty + 16 * i][tx + 16 * j] = (v.x + v.z) + (v.y + v.w);
        }
    __syncthreads();

    // ---- per-token f32 softmax + stable top-8, numpy rounding orders ----
    const int lane = tid & 63;
    const int wv   = tid >> 6;               // 4 waves, 8 tokens each
    float auxacc = 0.f;

    for (int tt = 0; tt < 8; ++tt) {
        const int t = wv * 8 + tt;
        const float s = lg[t][lane];

        float m = s;                          // max: exact, order-independent
        #pragma unroll
        for (int off = 32; off >= 1; off >>= 1)
            m = fmaxf(m, __shfl_xor(m, off));

        const float p = expf(s - m);
        lg[t][lane] = p;                      // own wave's row only
        __asm__ volatile("" ::: "memory");    // compiler barrier; DS in-order per wave

        // np.sum pairwise, n=64: 8 stride-8 serial chains + fixed combine
        float r0 = lg[t][0], r1 = lg[t][1], r2 = lg[t][2], r3 = lg[t][3];
        float r4 = lg[t][4], r5 = lg[t][5], r6 = lg[t][6], r7 = lg[t][7];
        #pragma unroll
        for (int i = 1; i < 8; ++i) {
            r0 += lg[t][8 * i + 0]; r1 += lg[t][8 * i + 1];
            r2 += lg[t][8 * i + 2]; r3 += lg[t][8 * i + 3];
            r4 += lg[t][8 * i + 4]; r5 += lg[t][8 * i + 5];
            r6 += lg[t][8 * i + 6]; r7 += lg[t][8 * i + 7];
        }
        const float S = ((r0 + r1) + (r2 + r3)) + ((r4 + r5) + (r6 + r7));

        const float score = p / S;            // IEEE f32 divide, matches np
        auxacc += score;

        // stable top-8: max with lowest-index tie-break (stable argsort)
        float cv = score;
        float myv = 0.f;
        int   myi = 0;
        #pragma unroll
        for (int i = 0; i < TOPK; ++i) {
            float v = cv;
            int idx = lane;
            #pragma unroll
            for (int off = 32; off >= 1; off >>= 1) {
                float v2 = __shfl_xor(v, off);
                int   i2 = __shfl_xor(idx, off);
                if (v2 > v || (v2 == v && i2 < idx)) { v = v2; idx = i2; }
            }
            if (lane == i)   { myv = v; myi = idx; }
            if (lane == idx) cv = -1.f;       // scores >= 0
        }

        // weight denom: np.sum n=8 -> serial ascending
        float S8 = 0.f;
        #pragma unroll
        for (int r = 0; r < TOPK; ++r) S8 += __shfl(myv, r);

        if (lane < TOPK) {
            const long o = (tok0 + t) * TOPK + lane;
            out[o]                     = (float)myi;   // expert_ids
            out[(long)NTOK * TOPK + o] = myv / S8;     // expert_weight
        }
    }

    const int b = blk >> 7;                  // 128 blocks per batch row
    atomicAdd(&wsum[b * NEXP + lane], auxacc);
}

__global__ void aux_finish(const float* __restrict__ wsum, float* __restrict__ out)
{
    const int lane = threadIdx.x;            // 64 threads
    float a = 0.f;
    #pragma unroll
    for (int b = 0; b < 4; ++b) {
        const float v = wsum[b * NEXP + lane] * (1.0f / 4096.0f);
        a = fmaf(v, v, a);
    }
    #pragma unroll
    for (int off = 32; off >= 1; off >>= 1)
        a += __shfl_xor(a, off);
    if (lane == 0)
        out[2L * NTOK * TOPK] = a * 0.25f * (float)NEXP * 0.01f;
}

extern "C" void kernel_launch(void* const* d_in, const int* in_sizes, int n_in,
                              void* d_out, int out_size, void* d_ws, size_t ws_size,
                              hipStream_t stream) {
    const float* h = (const float*)d_in[0];
    const float* W = (const float*)d_in[1];
    float* out  = (float*)d_out;
    float* wsum = (float*)d_ws;              // 256 f32

    hipMemsetAsync(d_ws, 0, 1024, stream);
    moe_gate_np<<<NBLK, 256, 0, stream>>>(h, W, out, wsum);
    aux_finish<<<1, 64, 0, stream>>>(wsum, out);
}